// Round 2
// baseline (440.127 us; speedup 1.0000x reference)
//
#include <hip/hip_runtime.h>
#include <hip/hip_bf16.h>

// Capsule EM routing, fused, votes recomputed in registers each pass.
// B=32, H=W=8, I=32 -> N=2048 per b, O=64, P=16, routings=3.
//
// Round-2 structure: block = 256 thr (4 waves) handles (b, 2 spatial sites);
// waves split the i-dimension 4x8. lane = output capsule o (softmax over O is
// a wave shuffle reduce). Per-block LDS reduce -> streaming partial write
// (no global atomics); stats kernel reduces the 32 partials per b.

#define NB 32
#define NN 2048
#define NO 64
#define NP 16
#define NSITES 64
#define SPG 2                 // sites per block
#define NGRP (NSITES / SPG)   // 32 groups per b
#define II 8                  // i's per wave (4 waves cover i=0..31)
#define EPSF 1e-7f
#define SLOTS 33              // 0..15 sum rr'v, 16..31 sum rr'v^2, 32 rps
#define PART_PER (SLOTS * NO)          // 2112 floats
#define PART_PER_B (NGRP * PART_PER)

// stats layout per b: [slot][o]: 0..15 mean, 16..31 = 0.5/var,
// 32 = zz_base = log(o_act+eps) - sum_p log(sigma_p+eps)

template <bool FIRST>
__global__ __launch_bounds__(256, 4) void accum_kernel(
    const float* __restrict__ pose,   // [B][N][16]
    const float* __restrict__ act,    // [B][N]
    const float* __restrict__ wmat,   // [I=32][O=64][16]
    const float* __restrict__ stats,  // [B][33][64] prev iter (null if FIRST)
    float* __restrict__ partial)      // [B][NGRP][33][64]
{
    __shared__ float pose_s[SPG * 32 * 16];   // 4 KB
    __shared__ float act_s[SPG * 32];
    __shared__ float red[PART_PER];           // 8.4 KB

    const int b = blockIdx.y;
    const int g = blockIdx.x;
    const int tid = threadIdx.x;

    for (int j = tid; j < PART_PER; j += 256) red[j] = 0.f;
    {
        const float4* psrc = (const float4*)(pose + ((size_t)b * NN + g * (SPG * 32)) * 16);
        ((float4*)pose_s)[tid] = psrc[tid];   // exactly 256 float4
        if (tid < SPG * 32) act_s[tid] = act[(size_t)b * NN + g * (SPG * 32) + tid];
    }
    __syncthreads();

    const int wv = tid >> 6;    // wave -> i-range
    const int o  = tid & 63;    // lane -> output capsule

    float m[16], i2v[16], zzb = 0.f;
    if (!FIRST) {
        const float* st = stats + (size_t)b * PART_PER;
        #pragma unroll
        for (int p = 0; p < 16; p++) m[p] = st[p * 64 + o];
        #pragma unroll
        for (int p = 0; p < 16; p++) i2v[p] = st[(16 + p) * 64 + o];
        zzb = st[32 * 64 + o];
    }

    float accR = 0.f, acc1[16], acc2[16];
    #pragma unroll
    for (int p = 0; p < 16; p++) { acc1[p] = 0.f; acc2[p] = 0.f; }

    float c0s[SPG], c1s[SPG];
    #pragma unroll
    for (int s = 0; s < SPG; s++) {
        int sp = g * SPG + s;
        c0s[s] = ((sp >> 3) + 0.5f) * 0.125f;
        c1s[s] = ((sp & 7) + 0.5f) * 0.125f;
    }

    const int i0 = wv * II;
    #pragma unroll 2
    for (int ii = 0; ii < II; ii++) {
        const int i = i0 + ii;
        const float4* wp = (const float4*)(wmat + ((size_t)i * 64 + o) * 16);
        float4 w0 = wp[0], w1 = wp[1], w2 = wp[2], w3 = wp[3];  // rows k=0..3
        #pragma unroll
        for (int s = 0; s < SPG; s++) {
            const int nl = s * 32 + i;
            const float4* pr4 = (const float4*)(pose_s + nl * 16);  // wave-uniform: broadcast
            float v[16];
            #pragma unroll
            for (int a = 0; a < 4; a++) {
                float4 pa = pr4[a];
                v[a * 4 + 0] = pa.x * w0.x + pa.y * w1.x + pa.z * w2.x + pa.w * w3.x;
                v[a * 4 + 1] = pa.x * w0.y + pa.y * w1.y + pa.z * w2.y + pa.w * w3.y;
                v[a * 4 + 2] = pa.x * w0.z + pa.y * w1.z + pa.z * w2.z + pa.w * w3.z;
                v[a * 4 + 3] = pa.x * w0.w + pa.y * w1.w + pa.z * w2.w + pa.w * w3.w;
            }
            v[0] += c0s[s];
            v[1] += c1s[s];

            float rr;
            if (FIRST) {
                rr = 1.0f / 64.0f;
            } else {
                float d = zzb;
                #pragma unroll
                for (int p = 0; p < 16; p++) {
                    float t = v[p] - m[p];
                    d -= t * t * i2v[p];
                }
                float mx = d;
                #pragma unroll
                for (int sh = 32; sh > 0; sh >>= 1) mx = fmaxf(mx, __shfl_xor(mx, sh, 64));
                float e = __expf(d - mx);
                float sum = e;
                #pragma unroll
                for (int sh = 32; sh > 0; sh >>= 1) sum += __shfl_xor(sum, sh, 64);
                rr = e / sum;
            }
            float rp = rr * act_s[nl];
            accR += rp;
            #pragma unroll
            for (int p = 0; p < 16; p++) {
                float t = rp * v[p];
                acc1[p] += t;
                acc2[p] += t * v[p];
            }
        }
    }

    // cross-wave reduce in LDS (2-way bank alias = free)
    atomicAdd(&red[32 * 64 + o], accR);
    #pragma unroll
    for (int p = 0; p < 16; p++) atomicAdd(&red[p * 64 + o], acc1[p]);
    #pragma unroll
    for (int p = 0; p < 16; p++) atomicAdd(&red[(16 + p) * 64 + o], acc2[p]);
    __syncthreads();

    float* dst = partial + ((size_t)b * NGRP + g) * PART_PER;
    for (int j = tid; j < PART_PER; j += 256) dst[j] = red[j];
}

__global__ __launch_bounds__(256) void stats_kernel(
    const float* __restrict__ partial,  // [B][NGRP][33][64]
    const float* __restrict__ beta_v,   // [64]
    const float* __restrict__ beta_a,   // [64]
    float* __restrict__ stats_out,      // [B][33][64] or null (final)
    float* __restrict__ out,            // null unless final
    float inv_temp)
{
    __shared__ float red[PART_PER];
    const int b = blockIdx.x;
    const int tid = threadIdx.x;
    const int wv = tid >> 6;
    const int o  = tid & 63;

    for (int j = tid; j < PART_PER; j += 256) red[j] = 0.f;
    __syncthreads();

    float s1[16], s2[16], rps = 0.f;
    #pragma unroll
    for (int p = 0; p < 16; p++) { s1[p] = 0.f; s2[p] = 0.f; }
    const float* pb = partial + (size_t)b * PART_PER_B;
    for (int g = wv; g < NGRP; g += 4) {
        const float* pg = pb + (size_t)g * PART_PER;
        rps += pg[32 * 64 + o];
        #pragma unroll
        for (int p = 0; p < 16; p++) {
            s1[p] += pg[p * 64 + o];
            s2[p] += pg[(16 + p) * 64 + o];
        }
    }
    atomicAdd(&red[32 * 64 + o], rps);
    #pragma unroll
    for (int p = 0; p < 16; p++) atomicAdd(&red[p * 64 + o], s1[p]);
    #pragma unroll
    for (int p = 0; p < 16; p++) atomicAdd(&red[(16 + p) * 64 + o], s2[p]);
    __syncthreads();

    if (tid < 64) {  // wave 0 finishes the per-(b,o) stats
        float rpt = red[32 * 64 + o];
        float mm[16], var[16], logsum = 0.f;
        #pragma unroll
        for (int p = 0; p < 16; p++) {
            float s1v = red[p * 64 + o];
            float s2v = red[(16 + p) * 64 + o];
            float mv = s1v / rpt;
            float vv = fmaxf(s2v / rpt - mv * mv, 0.f);
            mm[p] = mv;
            var[p] = vv;
            logsum += __logf(sqrtf(vv) + EPSF);
        }
        float cost = rpt * (16.0f * beta_v[o] + logsum);

        float cm = cost;
        #pragma unroll
        for (int sh = 32; sh > 0; sh >>= 1) cm += __shfl_xor(cm, sh, 64);
        cm *= (1.0f / 64.0f);
        float d = cost - cm;
        float cs = d * d;
        #pragma unroll
        for (int sh = 32; sh > 0; sh >>= 1) cs += __shfl_xor(cs, sh, 64);
        cs = sqrtf(cs * (1.0f / 64.0f));

        float x = inv_temp * (beta_a[o] + (cm - cost) / (cs + EPSF));
        float oa = 1.0f / (1.0f + __expf(-x));

        if (stats_out) {
            float* st = stats_out + (size_t)b * PART_PER;
            #pragma unroll
            for (int p = 0; p < 16; p++) st[p * 64 + o] = mm[p];
            #pragma unroll
            for (int p = 0; p < 16; p++) st[(16 + p) * 64 + o] = 0.5f / var[p];
            st[32 * 64 + o] = __logf(oa + EPSF) - logsum;
        }
        if (out) {
            float* op = out + ((size_t)b * 64 + o) * 16;
            #pragma unroll
            for (int p = 0; p < 16; p++) op[p] = mm[p];
            out[(size_t)NB * NO * NP + (size_t)b * 64 + o] = oa;
        }
    }
}

extern "C" void kernel_launch(void* const* d_in, const int* in_sizes, int n_in,
                              void* d_out, int out_size, void* d_ws, size_t ws_size,
                              hipStream_t stream) {
    const float* pose   = (const float*)d_in[0];  // (32,8,8,32,4,4)
    const float* act    = (const float*)d_in[1];  // (32,8,8,32)
    const float* wmat   = (const float*)d_in[2];  // (32,64,4,4)
    const float* beta_v = (const float*)d_in[3];  // (1,64)
    const float* beta_a = (const float*)d_in[4];  // (1,64)
    float* out = (float*)d_out;
    float* ws = (float*)d_ws;

    float* part   = ws;                                          // 8.65 MB
    float* stats0 = ws + (size_t)NB * PART_PER_B;                // 270 KB
    float* stats1 = stats0 + (size_t)NB * PART_PER;              // 270 KB
    // everything is fully written before read -> no memset needed

    dim3 grid(NGRP, NB);
    accum_kernel<true><<<grid, 256, 0, stream>>>(pose, act, wmat, nullptr, part);
    stats_kernel<<<NB, 256, 0, stream>>>(part, beta_v, beta_a, stats0, nullptr, 1.0f);
    accum_kernel<false><<<grid, 256, 0, stream>>>(pose, act, wmat, stats0, part);
    stats_kernel<<<NB, 256, 0, stream>>>(part, beta_v, beta_a, stats1, nullptr, 2.0f);
    accum_kernel<false><<<grid, 256, 0, stream>>>(pose, act, wmat, stats1, part);
    stats_kernel<<<NB, 256, 0, stream>>>(part, beta_v, beta_a, nullptr, out, 3.0f);
}

// Round 3
// 215.191 us; speedup vs baseline: 2.0453x; 2.0453x over previous
//
#include <hip/hip_runtime.h>
#include <hip/hip_bf16.h>

// Capsule EM routing, fused, votes recomputed in registers each pass.
// B=32, H=W=8, I=32 -> N=2048 per b, O=64, P=16, routings=3.
//
// Round-3: round-1's proven spill-free inner loop; decomposition changed to
// wave = (site, i-half of 16). Block = 256 thr = 4 waves = 2 sites x 2
// i-halves; grid (32,32) = 1024 blocks -> 16 waves/CU (50% occ ceiling).
// Per-wave global atomics as round 1 (writes ~34 MB total, cheap).

#define NB 32
#define NN 2048
#define NO 64
#define NP 16
#define EPSF 1e-7f

// accum layout per b: [slot][o], slots 0..15 = sum rr'*v, 16..31 = sum
// rr'*v^2, 32 = rps.
#define ACC_SLOTS 33
#define ACC_PER_B (ACC_SLOTS * NO)
#define ACC_TOTAL (NB * ACC_PER_B)

// stats layout per b: [slot][o]: 0..15 mean, 16..31 = 0.5/var,
// 32 = zz_base = log(o_act+eps) - sum_p log(sigma_p+eps)

template <bool FIRST>
__global__ __launch_bounds__(256) void accum_kernel(
    const float* __restrict__ pose,   // [B][N][16]
    const float* __restrict__ act,    // [B][N]
    const float* __restrict__ wmat,   // [I=32][O=64][16]
    const float* __restrict__ stats,  // [B][33][64] prev iter (null if FIRST)
    float* __restrict__ accum)        // [B][33][64] (pre-zeroed)
{
    __shared__ float pose_s[2 * 32 * 16];  // 4 KB: this block's 2 sites
    __shared__ float act_s[64];

    const int b = blockIdx.y;
    const int g = blockIdx.x;   // site-pair index 0..31
    const int tid = threadIdx.x;

    {
        const float4* psrc = (const float4*)(pose + ((size_t)b * NN + g * 64) * 16);
        ((float4*)pose_s)[tid] = psrc[tid];   // exactly 256 float4
        if (tid < 64) act_s[tid] = act[(size_t)b * NN + g * 64 + tid];
    }
    __syncthreads();

    const int wv = tid >> 6;        // 4 waves
    const int o  = tid & 63;        // lane = output capsule
    const int sl = wv >> 1;         // site within pair: 0/1
    const int i0 = (wv & 1) * 16;   // i-half: 0..15 / 16..31

    float m[16], i2v[16], zzb = 0.f;
    if (!FIRST) {
        const float* st = stats + (size_t)b * ACC_PER_B;
        #pragma unroll
        for (int p = 0; p < 16; p++) m[p] = st[p * 64 + o];
        #pragma unroll
        for (int p = 0; p < 16; p++) i2v[p] = st[(16 + p) * 64 + o];
        zzb = st[32 * 64 + o];
    }

    float accR = 0.f, acc1[16], acc2[16];
    #pragma unroll
    for (int p = 0; p < 16; p++) { acc1[p] = 0.f; acc2[p] = 0.f; }

    const int sp = g * 2 + sl;      // spatial site 0..63
    const float c0 = ((sp >> 3) + 0.5f) * 0.125f;
    const float c1 = ((sp & 7) + 0.5f) * 0.125f;

    for (int ii = 0; ii < 16; ii++) {
        const int i = i0 + ii;
        const float4* wp = (const float4*)(wmat + ((size_t)i * 64 + o) * 16);
        float4 w0 = wp[0], w1 = wp[1], w2 = wp[2], w3 = wp[3];  // rows k=0..3
        const int nl = sl * 32 + i;
        const float* pr = pose_s + nl * 16;  // wave-uniform addr -> broadcast
        float v[16];
        #pragma unroll
        for (int a = 0; a < 4; a++) {
            float pa0 = pr[a * 4 + 0], pa1 = pr[a * 4 + 1];
            float pa2 = pr[a * 4 + 2], pa3 = pr[a * 4 + 3];
            v[a * 4 + 0] = pa0 * w0.x + pa1 * w1.x + pa2 * w2.x + pa3 * w3.x;
            v[a * 4 + 1] = pa0 * w0.y + pa1 * w1.y + pa2 * w2.y + pa3 * w3.y;
            v[a * 4 + 2] = pa0 * w0.z + pa1 * w1.z + pa2 * w2.z + pa3 * w3.z;
            v[a * 4 + 3] = pa0 * w0.w + pa1 * w1.w + pa2 * w2.w + pa3 * w3.w;
        }
        v[0] += c0;
        v[1] += c1;

        float rr;
        if (FIRST) {
            rr = 1.0f / 64.0f;
        } else {
            float d = zzb;
            #pragma unroll
            for (int p = 0; p < 16; p++) {
                float t = v[p] - m[p];
                d -= t * t * i2v[p];
            }
            // softmax over the 64 o-lanes
            float mx = d;
            #pragma unroll
            for (int s = 32; s > 0; s >>= 1) mx = fmaxf(mx, __shfl_xor(mx, s, 64));
            float e = __expf(d - mx);
            float sum = e;
            #pragma unroll
            for (int s = 32; s > 0; s >>= 1) sum += __shfl_xor(sum, s, 64);
            rr = e / sum;
        }
        float rp = rr * act_s[nl];
        accR += rp;
        #pragma unroll
        for (int p = 0; p < 16; p++) {
            acc1[p] += rp * v[p];
            acc2[p] += rp * v[p] * v[p];
        }
    }

    float* ac = accum + (size_t)b * ACC_PER_B;
    atomicAdd(ac + 32 * 64 + o, accR);
    #pragma unroll
    for (int p = 0; p < 16; p++) atomicAdd(ac + p * 64 + o, acc1[p]);
    #pragma unroll
    for (int p = 0; p < 16; p++) atomicAdd(ac + (16 + p) * 64 + o, acc2[p]);
}

__global__ __launch_bounds__(64) void stats_kernel(
    const float* __restrict__ accum,   // [B][33][64]
    const float* __restrict__ beta_v,  // [64]
    const float* __restrict__ beta_a,  // [64]
    float* __restrict__ stats_out,     // [B][33][64] or null (final)
    float* __restrict__ out,           // null unless final
    float inv_temp)
{
    const int b = blockIdx.x;
    const int o = threadIdx.x;  // 64 threads = 1 wave
    const float* ac = accum + (size_t)b * ACC_PER_B;

    float rps = ac[32 * 64 + o];
    float m[16], var[16];
    float logsum = 0.f;
    #pragma unroll
    for (int p = 0; p < 16; p++) {
        float s1 = ac[p * 64 + o];
        float s2 = ac[(16 + p) * 64 + o];
        float mm = s1 / rps;
        float vv = fmaxf(s2 / rps - mm * mm, 0.f);
        m[p] = mm;
        var[p] = vv;
        logsum += __logf(sqrtf(vv) + EPSF);
    }
    float cost = rps * (16.0f * beta_v[o] + logsum);

    // mean over O
    float cm = cost;
    #pragma unroll
    for (int s = 32; s > 0; s >>= 1) cm += __shfl_xor(cm, s, 64);
    cm *= (1.0f / 64.0f);
    // population stdv over O
    float d = cost - cm;
    float cs = d * d;
    #pragma unroll
    for (int s = 32; s > 0; s >>= 1) cs += __shfl_xor(cs, s, 64);
    cs = sqrtf(cs * (1.0f / 64.0f));

    float x = inv_temp * (beta_a[o] + (cm - cost) / (cs + EPSF));
    float oa = 1.0f / (1.0f + __expf(-x));

    if (stats_out) {
        float* st = stats_out + (size_t)b * ACC_PER_B;
        #pragma unroll
        for (int p = 0; p < 16; p++) st[p * 64 + o] = m[p];
        #pragma unroll
        for (int p = 0; p < 16; p++) st[(16 + p) * 64 + o] = 0.5f / var[p];
        st[32 * 64 + o] = __logf(oa + EPSF) - logsum;
    }
    if (out) {
        float* op = out + ((size_t)b * 64 + o) * 16;
        #pragma unroll
        for (int p = 0; p < 16; p++) op[p] = m[p];
        out[(size_t)NB * NO * NP + (size_t)b * 64 + o] = oa;
    }
}

extern "C" void kernel_launch(void* const* d_in, const int* in_sizes, int n_in,
                              void* d_out, int out_size, void* d_ws, size_t ws_size,
                              hipStream_t stream) {
    const float* pose   = (const float*)d_in[0];  // (32,8,8,32,4,4)
    const float* act    = (const float*)d_in[1];  // (32,8,8,32)
    const float* wmat   = (const float*)d_in[2];  // (32,64,4,4)
    const float* beta_v = (const float*)d_in[3];  // (1,64)
    const float* beta_a = (const float*)d_in[4];  // (1,64)
    float* out = (float*)d_out;
    float* ws = (float*)d_ws;

    float* accum0 = ws;
    float* accum1 = ws + ACC_TOTAL;
    float* accum2 = ws + 2 * (size_t)ACC_TOTAL;
    float* stats0 = ws + 3 * (size_t)ACC_TOTAL;
    float* stats1 = ws + 4 * (size_t)ACC_TOTAL;

    // zero the three atomic-accumulator regions (ws is poisoned every call)
    hipMemsetAsync(ws, 0, 3 * (size_t)ACC_TOTAL * sizeof(float), stream);

    dim3 grid(32, NB);  // 32 site-pairs x 32 b = 1024 blocks
    accum_kernel<true><<<grid, 256, 0, stream>>>(pose, act, wmat, nullptr, accum0);
    stats_kernel<<<NB, 64, 0, stream>>>(accum0, beta_v, beta_a, stats0, nullptr, 1.0f);
    accum_kernel<false><<<grid, 256, 0, stream>>>(pose, act, wmat, stats0, accum1);
    stats_kernel<<<NB, 64, 0, stream>>>(accum1, beta_v, beta_a, stats1, nullptr, 2.0f);
    accum_kernel<false><<<grid, 256, 0, stream>>>(pose, act, wmat, stats1, accum2);
    stats_kernel<<<NB, 64, 0, stream>>>(accum2, beta_v, beta_a, nullptr, out, 3.0f);
}